// Round 5
// baseline (250.048 us; speedup 1.0000x reference)
//
#include <hip/hip_runtime.h>

// EMA along contiguous T axis — barrier-free streaming waves, software pipeline.
//
// Shapes: mag_spec [NSEQ=4112, T=6000] f32, init [NSEQ] f32, w [1] f32 (0.04).
//
// Windows of 1500 outputs tile the array contiguously (4 windows/sequence,
// NWIN = 4*NSEQ). Each 64-lane wave is INDEPENDENT (wave-private LDS, no
// __syncthreads): grid-stride over windows with a 2-deep pipeline — next
// window's 8 coalesced dwordx4 loads are issued before this window's compute,
// so ~8KB/wave stays in flight through the whole compute phase. Cross-lane
// LDS visibility within the wave is enforced with `s_waitcnt lgkmcnt(0)`
// (inline asm) — never vmcnt, so the pipeline is never drained.
//
// Halo = 356 preceding elements reconstructs incoming state (0.96^356 ~ 0);
// chunk-0 halo is overwritten with the init value (exact: EMA fixed point).
// K=29 floats/lane: stride 29 coprime with 32 banks -> conflict-free chains.
// Output stores are nontemporal (keep LLC for the input stream).

constexpr int T_LEN  = 6000;
constexpr int OUT_F4 = 375;          // 1500 floats out per window
constexpr int K      = 29;           // floats per lane
constexpr int E      = 64 * K;       // 1856-float window
constexpr int EF4    = E / 4;        // 464
constexpr int H      = E - 1500;     // 356-float halo
constexpr int HF4    = H / 4;        // 89
constexpr int WPS    = 4;            // windows per sequence
constexpr int BLOCK  = 256;          // 4 independent waves
constexpr int NBLK   = 1024;         // 4 blocks/CU resident (LDS allows 5)

typedef float vfloat4 __attribute__((ext_vector_type(4)));  // clang-native for NT store

__device__ __forceinline__ void load_window(float4 v[8], const float4* __restrict__ g4,
                                            int win, int lane) {
    const int base = win * OUT_F4 - HF4;   // may be -89 for win 0: clamp
    #pragma unroll
    for (int r = 0; r < 8; ++r) {
        const int f = r * 64 + lane;
        if (f < EF4) {
            int idx = base + f;
            v[r] = g4[idx < 0 ? 0 : idx];
        }
    }
}

__global__ __launch_bounds__(BLOCK) void ema_kernel(
    const float* __restrict__ x,      // [NSEQ*T]
    const float* __restrict__ init,   // [NSEQ]
    const float* __restrict__ wptr,   // [1]
    float* __restrict__ out,          // [NSEQ*T]
    int nwin)
{
    __shared__ __align__(16) float tile[4][E];   // wave-private regions
    const int wv   = threadIdx.x >> 6;
    const int lane = threadIdx.x & 63;
    float* T = tile[wv];

    const int gwave  = blockIdx.x * 4 + wv;
    const int stride = gridDim.x * 4;

    const float w = fminf(fmaxf(wptr[0], 0.0f), 1.0f);
    const float d = 1.0f - w;
    const float d2 = d * d, d4 = d2 * d2, d8 = d4 * d4, d16 = d8 * d8;
    const float d29 = d16 * d8 * d4 * d;

    const float4* g4 = (const float4*)x;
    float4*       o4 = (float4*)out;

    // ---- prologue: load first window into registers ----
    float4 cur[8];
    int win = gwave;
    if (win < nwin) load_window(cur, g4, win, lane);

    for (; win < nwin; win += stride) {
        // ---- stage cur -> wave-private LDS (coalesced b128) ----
        #pragma unroll
        for (int r = 0; r < 8; ++r) {
            const int f = r * 64 + lane;
            if (f < EF4) *(float4*)&T[f * 4] = cur[r];
        }

        const float iv = init[win >> 2];           // WPS=4, wave-uniform
        if ((win & (WPS - 1)) == 0) {
            // chunk 0: halo := init value (exact fixed point)
            const float4 ivv = make_float4(iv, iv, iv, iv);
            #pragma unroll
            for (int r = 0; r < 2; ++r) {
                const int f = r * 64 + lane;
                if (f < HF4) *(float4*)&T[f * 4] = ivv;
            }
        }

        // ---- issue NEXT window's loads now: in flight through compute ----
        const int nxtwin = win + stride;
        float4 nxt[8];
        if (nxtwin < nwin) load_window(nxt, g4, nxtwin, lane);

        // ensure staging ds_writes retired before cross-lane reads (lgkm only,
        // vmcnt untouched -> nxt loads stay outstanding)
        asm volatile("s_waitcnt lgkmcnt(0)" ::: "memory");

        // ---- pass 1: per-lane affine map (A = d^29, B) over K elements ----
        const float* lx = &T[lane * K];
        float b = 0.0f;
        #pragma unroll
        for (int j = 0; j < K; ++j) b = fmaf(w, lx[j], d * b);
        float a = d29;

        // ---- in-wave inclusive shfl scan of affine maps ----
        #pragma unroll
        for (int off = 1; off < 64; off <<= 1) {
            float pa = __shfl_up(a, off, 64);
            float pb = __shfl_up(b, off, 64);
            if (lane >= off) {
                b = fmaf(a, pb, b);   // earlier map first, then current
                a = a * pa;
            }
        }
        float ea = __shfl_up(a, 1, 64);
        float eb = __shfl_up(b, 1, 64);
        if (lane == 0) { ea = 1.0f; eb = 0.0f; }
        const float s_in = fmaf(ea, iv, eb);   // iv decays through halo for chunk>0

        // ---- pass 2: recompute with correct incoming state, in place ----
        float* lxm = &T[lane * K];
        float acc = s_in;
        #pragma unroll
        for (int j = 0; j < K; ++j) {
            acc = fmaf(w, lxm[j], d * acc);
            lxm[j] = acc;
        }

        // results visible cross-lane before coalesced store reads
        asm volatile("s_waitcnt lgkmcnt(0)" ::: "memory");

        // ---- coalesced nontemporal store of the 375 output float4 ----
        vfloat4* ow = (vfloat4*)(o4 + (size_t)win * OUT_F4);
        #pragma unroll
        for (int s = 0; s < 6; ++s) {
            const int f = s * 64 + lane;
            if (f < OUT_F4) {
                vfloat4 v = *(const vfloat4*)&T[H + f * 4];
                __builtin_nontemporal_store(v, &ow[f]);
            }
        }

        // ---- rotate pipeline ----
        #pragma unroll
        for (int r = 0; r < 8; ++r) cur[r] = nxt[r];
    }
}

extern "C" void kernel_launch(void* const* d_in, const int* in_sizes, int n_in,
                              void* d_out, int out_size, void* d_ws, size_t ws_size,
                              hipStream_t stream) {
    const float* mag_spec = (const float*)d_in[0];
    const float* initial_state = (const float*)d_in[1];
    const float* weights = (const float*)d_in[2];
    float* out = (float*)d_out;

    const int nseq = in_sizes[1];    // 8*2*257 = 4112
    const int nwin = nseq * WPS;     // 16448 windows tile the array exactly

    ema_kernel<<<NBLK, BLOCK, 0, stream>>>(mag_spec, initial_state, weights, out, nwin);
}